// Round 6
// baseline (898.389 us; speedup 1.0000x reference)
//
#include <hip/hip_runtime.h>
#include <hip/hip_bf16.h>

#define NN 50000
#define NE 800000

typedef unsigned int u32;
typedef unsigned short u16;
typedef __attribute__((ext_vector_type(8))) short short8;   // 8 bf16 = 4 VGPR
typedef __attribute__((ext_vector_type(4))) float f32x4;    // MFMA C/D

__device__ __forceinline__ float silu_f(float x) {
    return x * (1.0f / (1.0f + __expf(-x)));
}
__device__ __forceinline__ float bf2f(u16 u) {
    return __uint_as_float(((u32)u) << 16);
}
__device__ __forceinline__ u16 f2bf(float f) {
    u32 x = __float_as_uint(f);
    return (u16)((x + 0x7fffu + ((x >> 16) & 1u)) >> 16);   // RNE
}
__device__ __forceinline__ u32 pk_bf16(float a, float b) {  // proven f2bf path
    return (u32)f2bf(a) | ((u32)f2bf(b) << 16);
}

// ---------------------------------------------------------------------------
// Sort-by-DST machinery: histogram -> 2-level exclusive scan -> scatter ranks
// ---------------------------------------------------------------------------
__global__ __launch_bounds__(256) void k_hist(const int* __restrict__ ei, u32* __restrict__ cnt) {
    int e = blockIdx.x * 256 + threadIdx.x;
    atomicAdd(&cnt[ei[NE + e]], 1u);
}

__global__ __launch_bounds__(256) void k_scan_a(const u32* __restrict__ cnt, u32* __restrict__ part) {
    __shared__ u32 sb[256];
    int t = threadIdx.x, i = blockIdx.x * 256 + t;
    u32 v = (i < NN) ? cnt[i] : 0u;
    sb[t] = v; __syncthreads();
    for (int off = 128; off > 0; off >>= 1) { if (t < off) sb[t] += sb[t + off]; __syncthreads(); }
    if (t == 0) part[blockIdx.x] = sb[0];
}

__global__ __launch_bounds__(256) void k_scan_b(u32* __restrict__ part, int nparts) {
    __shared__ u32 sb[256];
    int t = threadIdx.x;
    u32 v = (t < nparts) ? part[t] : 0u;
    sb[t] = v; __syncthreads();
    for (int off = 1; off < 256; off <<= 1) {
        u32 x = (t >= off) ? sb[t - off] : 0u; __syncthreads();
        sb[t] += x; __syncthreads();
    }
    if (t < nparts) part[t] = sb[t] - v;          // exclusive
}

__global__ __launch_bounds__(256) void k_scan_c(const u32* __restrict__ cnt, const u32* __restrict__ part,
                                                u32* __restrict__ row, u32* __restrict__ rowcur) {
    __shared__ u32 sb[256];
    int t = threadIdx.x, i = blockIdx.x * 256 + t;
    u32 v = (i < NN) ? cnt[i] : 0u;
    sb[t] = v; __syncthreads();
    for (int off = 1; off < 256; off <<= 1) {
        u32 x = (t >= off) ? sb[t - off] : 0u; __syncthreads();
        sb[t] += x; __syncthreads();
    }
    if (i < NN) {
        u32 ex = part[blockIdx.x] + sb[t] - v;
        row[i] = ex; rowcur[i] = ex;
    }
    if (i == 0) row[NN] = NE;
}

__global__ __launch_bounds__(256) void k_scatter(const int* __restrict__ ei, u32* __restrict__ rowcur,
                                                 u32* __restrict__ rank, u32* __restrict__ ssrc,
                                                 u16* __restrict__ sdst) {
    int e = blockIdx.x * 256 + threadIdx.x;
    u32 s_ = (u32)ei[e];
    u32 d_ = (u32)ei[NE + e];
    u32 pos = atomicAdd(&rowcur[d_], 1u);
    rank[e] = pos;
    ssrc[pos] = s_;
    sdst[pos] = (u16)d_;
}

// ---------------------------------------------------------------------------
// Wt transpose: WtT[g][m*64+f] = bf16(W_tp[f][m][g])   [64][576] bf16
// ---------------------------------------------------------------------------
__global__ __launch_bounds__(256) void k_wt(const float* __restrict__ Wtp, u16* __restrict__ WtT) {
    int o = blockIdx.x * 256 + threadIdx.x;     // 0..36863
    int g = o / 576, k = o % 576;
    int m = k >> 6, f = k & 63;
    WtT[o] = f2bf(Wtp[f * 576 + m * 64 + g]);
}

// ---------------------------------------------------------------------------
// K1: per-edge weight MLP; writes s (bf16, padded to 12) at dst-sorted pos.
// (field-proven since round 2)
// ---------------------------------------------------------------------------
__global__ __launch_bounds__(256) void k_edge_mlp(
    const float* __restrict__ edge_attr, const float* __restrict__ edge_sh,
    const float* __restrict__ W1, const float* __restrict__ b1,
    const float* __restrict__ W2, const float* __restrict__ b2,
    const u32* __restrict__ rank,
    u16* __restrict__ s_sorted)            // [NE][12] bf16 at rank[e]
{
    __shared__ float sAttr[256 * 36];
    const int t  = threadIdx.x;
    const int e0 = blockIdx.x * 256;

    const float* ga = edge_attr + (size_t)e0 * 32;
    #pragma unroll
    for (int k = 0; k < 32; ++k) {
        int i = k * 256 + t;
        sAttr[(i >> 5) * 36 + (i & 31)] = ga[i];
    }
    __syncthreads();

    float a[32];
    #pragma unroll
    for (int q = 0; q < 8; ++q) {
        float4 v = *(const float4*)&sAttr[t * 36 + q * 4];
        a[4*q+0] = v.x; a[4*q+1] = v.y; a[4*q+2] = v.z; a[4*q+3] = v.w;
    }

    float hid[64];
    #pragma unroll
    for (int h = 0; h < 64; ++h) hid[h] = b1[h];
    for (int d = 0; d < 32; ++d) {
        const float ad = a[d];
        const float* wr = W1 + d * 64;
        #pragma unroll
        for (int h = 0; h < 64; ++h) hid[h] += ad * wr[h];
    }

    float w[9];
    #pragma unroll
    for (int m = 0; m < 9; ++m) w[m] = b2[m];
    for (int h = 0; h < 64; ++h) {
        const float hv = silu_f(hid[h]);
        const float* w2r = W2 + h * 9;
        #pragma unroll
        for (int m = 0; m < 9; ++m) w[m] += hv * w2r[m];
    }

    const size_t e = (size_t)e0 + t;
    const float* sh = edge_sh + e * 9;
    u16 sw[12];
    #pragma unroll
    for (int m = 0; m < 9; ++m) sw[m] = f2bf(sh[m] * w[m]);
    sw[9] = sw[10] = sw[11] = 0;

    u16* dp = s_sorted + (size_t)rank[e] * 12;
    ushort4 v0{sw[0], sw[1], sw[2],  sw[3]};
    ushort4 v1{sw[4], sw[5], sw[6],  sw[7]};
    ushort4 v2{sw[8], sw[9], sw[10], sw[11]};
    *(ushort4*)(dp + 0) = v0;
    *(ushort4*)(dp + 4) = v1;
    *(ushort4*)(dp + 8) = v2;
}

// ---------------------------------------------------------------------------
// K3: MFMA combine, bisection form: no LDS, no segmented reduce, no asm.
// Block = 256 dst-sorted edges, 4 waves, each wave 4 A-tiles of 16 edges.
// A-frag built from feat[src]*s via proven f2bf packing; B from WtT.
// Scatter: direct per-fragment f32 atomics (dst-sorted => same-line bursts,
// L2 write-combines; r2 measured this pattern at 12.5 MB WRITE_SIZE).
// ---------------------------------------------------------------------------
__global__ __launch_bounds__(256) void k_combine_mfma(
    const u32* __restrict__ ssrc, const u16* __restrict__ sdst,
    const u16* __restrict__ s_sorted,
    const float* __restrict__ feat, const u16* __restrict__ WtT,
    float* __restrict__ out)
{
    const int t  = threadIdx.x;
    const int w  = t >> 6;
    const int l  = t & 63;
    const int p0 = blockIdx.x * 256;
    const int rbase = w << 6;

    // this lane's A-row edge for each et-tile
    u32 srcr[4];
    float sreg[4][9];
    #pragma unroll
    for (int et = 0; et < 4; ++et) {
        const int p = p0 + rbase + (et << 4) + (l & 15);
        srcr[et] = ssrc[p];
        const u16* sp = s_sorted + (size_t)p * 12;
        #pragma unroll
        for (int m = 0; m < 9; ++m) sreg[et][m] = bf2f(sp[m]);
    }

    f32x4 acc[4][4] = {};
    #pragma unroll
    for (int fhalf = 0; fhalf < 2; ++fhalf) {
        float hv[4][8];
        #pragma unroll
        for (int et = 0; et < 4; ++et) {
            const float* hp = feat + (size_t)srcr[et] * 64 + (fhalf << 5) + ((l >> 4) << 3);
            float4 v0 = *(const float4*)hp;
            float4 v1 = *(const float4*)(hp + 4);
            hv[et][0] = v0.x; hv[et][1] = v0.y; hv[et][2] = v0.z; hv[et][3] = v0.w;
            hv[et][4] = v1.x; hv[et][5] = v1.y; hv[et][6] = v1.z; hv[et][7] = v1.w;
        }
        #pragma unroll
        for (int m = 0; m < 9; ++m) {
            const int tt = (m << 1) + fhalf;          // K-slice: k = tt*32 ..
            short8 bfr[4];
            #pragma unroll
            for (int gt = 0; gt < 4; ++gt)
                bfr[gt] = *(const short8*)(WtT +
                    (size_t)(((gt << 4) + (l & 15)) * 576 + tt * 32 + ((l >> 4) << 3)));
            #pragma unroll
            for (int et = 0; et < 4; ++et) {
                const float s = sreg[et][m];
                union { u32 u[4]; short8 v; } A;
                A.u[0] = pk_bf16(hv[et][0] * s, hv[et][1] * s);
                A.u[1] = pk_bf16(hv[et][2] * s, hv[et][3] * s);
                A.u[2] = pk_bf16(hv[et][4] * s, hv[et][5] * s);
                A.u[3] = pk_bf16(hv[et][6] * s, hv[et][7] * s);
                #pragma unroll
                for (int gt = 0; gt < 4; ++gt)
                    acc[et][gt] = __builtin_amdgcn_mfma_f32_16x16x32_bf16(A.v, bfr[gt], acc[et][gt], 0, 0, 0);
            }
        }
    }

    // ---- direct scatter: dst per C-row, one atomic per fragment element ----
    #pragma unroll
    for (int et = 0; et < 4; ++et) {
        #pragma unroll
        for (int rg = 0; rg < 4; ++rg) {
            const int eloc = rbase + (et << 4) + ((l >> 4) << 2) + rg;  // C row
            const int dst  = sdst[p0 + eloc];
            float* orow = out + (size_t)dst * 64 + (l & 15);
            #pragma unroll
            for (int gt = 0; gt < 4; ++gt)
                atomicAdd(orow + (gt << 4), acc[et][gt][rg] * 0.25f);   // 1/sqrt(16)
        }
    }
}

// ---------------------------------------------------------------------------
// K4: FiLM, in-place on d_out.
// ---------------------------------------------------------------------------
__global__ __launch_bounds__(256) void k_film(
    const float* __restrict__ c_noise,
    const float* __restrict__ Wn1, const float* __restrict__ bn1,
    const float* __restrict__ Wn2, const float* __restrict__ bn2,
    float* __restrict__ out)
{
    const int n    = (blockIdx.x * 256 + threadIdx.x) >> 6;
    const int lane = threadIdx.x & 63;
    const float c  = c_noise[n];
    const float hid = silu_f(fmaf(c, Wn1[lane], bn1[lane]));
    float g = bn2[lane], b = bn2[64 + lane];
    for (int h = 0; h < 64; ++h) {
        const float hv = __shfl(hid, h, 64);
        g = fmaf(hv, Wn2[h * 128 + lane],      g);
        b = fmaf(hv, Wn2[h * 128 + 64 + lane], b);
    }
    const size_t i = (size_t)n * 64 + lane;
    out[i] = fmaf(out[i], 1.f + g, b);
}

// ---------------------------------------------------------------------------
extern "C" void kernel_launch(void* const* d_in, const int* in_sizes, int n_in,
                              void* d_out, int out_size, void* d_ws, size_t ws_size,
                              hipStream_t stream) {
    const float* features   = (const float*)d_in[0];
    const int*   edge_index = (const int*)  d_in[1];
    const float* edge_attr  = (const float*)d_in[2];
    const float* edge_sh    = (const float*)d_in[3];
    const float* c_noise    = (const float*)d_in[4];
    const float* W1  = (const float*)d_in[5];
    const float* b1  = (const float*)d_in[6];
    const float* W2  = (const float*)d_in[7];
    const float* b2  = (const float*)d_in[8];
    const float* Wtp = (const float*)d_in[9];
    const float* Wn1 = (const float*)d_in[10];
    const float* bn1 = (const float*)d_in[11];
    const float* Wn2 = (const float*)d_in[12];
    const float* bn2 = (const float*)d_in[13];
    float* out = (float*)d_out;

    char* ws = (char*)d_ws;
    u16* s_sorted = (u16*)(ws);                    // 19,200,000 B
    u32* ssrc     = (u32*)(ws + 19200000);         //  3,200,000 B
    u32* rank     = (u32*)(ws + 22400000);         //  3,200,000 B
    u16* sdst     = (u16*)(ws + 25600000);         //  1,600,000 B
    u32* row      = (u32*)(ws + 27200000);         //    200,016 B (NN+1)
    u32* rowcur   = (u32*)(ws + 27400016);         //    200,000 B
    u32* cnt      = (u32*)(ws + 27600016);         //    200,000 B
    u32* part     = (u32*)(ws + 27800016);         //      1,024 B
    u16* WtT      = (u16*)(ws + 27801040);         //     73,728 B  (end ~27.9 MB)

    const int nparts = (NN + 255) / 256;           // 196

    hipMemsetAsync(cnt, 0, (size_t)NN * 4, stream);
    hipMemsetAsync(out, 0, (size_t)NN * 64 * sizeof(float), stream);

    k_hist   <<<NE / 256, 256, 0, stream>>>(edge_index, cnt);
    k_scan_a <<<nparts, 256, 0, stream>>>(cnt, part);
    k_scan_b <<<1, 256, 0, stream>>>(part, nparts);
    k_scan_c <<<nparts, 256, 0, stream>>>(cnt, part, row, rowcur);
    k_scatter<<<NE / 256, 256, 0, stream>>>(edge_index, rowcur, rank, ssrc, sdst);

    k_wt      <<<(576 * 64) / 256, 256, 0, stream>>>(Wtp, WtT);
    k_edge_mlp<<<NE / 256, 256, 0, stream>>>(edge_attr, edge_sh, W1, b1, W2, b2, rank, s_sorted);

    k_combine_mfma<<<NE / 256, 256, 0, stream>>>(ssrc, sdst, s_sorted,
                                                 features, WtT, out);

    k_film<<<(NN * 64) / 256, 256, 0, stream>>>(c_noise, Wn1, bn1, Wn2, bn2, out);
}

// Round 7
// 435.426 us; speedup vs baseline: 2.0632x; 2.0632x over previous
//
#include <hip/hip_runtime.h>
#include <hip/hip_bf16.h>

#define NN 50000
#define NE 800000

typedef unsigned int u32;
typedef unsigned short u16;
typedef __attribute__((ext_vector_type(8))) short short8;   // 8 bf16 = 4 VGPR
typedef __attribute__((ext_vector_type(4))) float f32x4;    // MFMA C/D

__device__ __forceinline__ float silu_f(float x) {
    return x * (1.0f / (1.0f + __expf(-x)));
}
__device__ __forceinline__ float bf2f(u16 u) {
    return __uint_as_float(((u32)u) << 16);
}
__device__ __forceinline__ u16 f2bf(float f) {
    u32 x = __float_as_uint(f);
    return (u16)((x + 0x7fffu + ((x >> 16) & 1u)) >> 16);   // RNE
}
__device__ __forceinline__ u32 pk_bf16(float a, float b) {  // proven f2bf path
    return (u32)f2bf(a) | ((u32)f2bf(b) << 16);
}

// ---------------------------------------------------------------------------
// Sort-by-DST machinery: histogram -> 2-level exclusive scan -> scatter ranks
// ---------------------------------------------------------------------------
__global__ __launch_bounds__(256) void k_hist(const int* __restrict__ ei, u32* __restrict__ cnt) {
    int e = blockIdx.x * 256 + threadIdx.x;
    atomicAdd(&cnt[ei[NE + e]], 1u);
}

__global__ __launch_bounds__(256) void k_scan_a(const u32* __restrict__ cnt, u32* __restrict__ part) {
    __shared__ u32 sb[256];
    int t = threadIdx.x, i = blockIdx.x * 256 + t;
    u32 v = (i < NN) ? cnt[i] : 0u;
    sb[t] = v; __syncthreads();
    for (int off = 128; off > 0; off >>= 1) { if (t < off) sb[t] += sb[t + off]; __syncthreads(); }
    if (t == 0) part[blockIdx.x] = sb[0];
}

__global__ __launch_bounds__(256) void k_scan_b(u32* __restrict__ part, int nparts) {
    __shared__ u32 sb[256];
    int t = threadIdx.x;
    u32 v = (t < nparts) ? part[t] : 0u;
    sb[t] = v; __syncthreads();
    for (int off = 1; off < 256; off <<= 1) {
        u32 x = (t >= off) ? sb[t - off] : 0u; __syncthreads();
        sb[t] += x; __syncthreads();
    }
    if (t < nparts) part[t] = sb[t] - v;          // exclusive
}

__global__ __launch_bounds__(256) void k_scan_c(const u32* __restrict__ cnt, const u32* __restrict__ part,
                                                u32* __restrict__ row, u32* __restrict__ rowcur) {
    __shared__ u32 sb[256];
    int t = threadIdx.x, i = blockIdx.x * 256 + t;
    u32 v = (i < NN) ? cnt[i] : 0u;
    sb[t] = v; __syncthreads();
    for (int off = 1; off < 256; off <<= 1) {
        u32 x = (t >= off) ? sb[t - off] : 0u; __syncthreads();
        sb[t] += x; __syncthreads();
    }
    if (i < NN) {
        u32 ex = part[blockIdx.x] + sb[t] - v;
        row[i] = ex; rowcur[i] = ex;
    }
    if (i == 0) row[NN] = NE;
}

__global__ __launch_bounds__(256) void k_scatter(const int* __restrict__ ei, u32* __restrict__ rowcur,
                                                 u32* __restrict__ rank, u32* __restrict__ ssrc,
                                                 u16* __restrict__ sdst) {
    int e = blockIdx.x * 256 + threadIdx.x;
    u32 s_ = (u32)ei[e];
    u32 d_ = (u32)ei[NE + e];
    u32 pos = atomicAdd(&rowcur[d_], 1u);
    rank[e] = pos;
    ssrc[pos] = s_;
    sdst[pos] = (u16)d_;
}

// ---------------------------------------------------------------------------
// Wt transpose: WtT[g][m*64+f] = bf16(W_tp[f][m][g])   [64][576] bf16
// ---------------------------------------------------------------------------
__global__ __launch_bounds__(256) void k_wt(const float* __restrict__ Wtp, u16* __restrict__ WtT) {
    int o = blockIdx.x * 256 + threadIdx.x;     // 0..36863
    int g = o / 576, k = o % 576;
    int m = k >> 6, f = k & 63;
    WtT[o] = f2bf(Wtp[f * 576 + m * 64 + g]);
}

// ---------------------------------------------------------------------------
// K1: per-edge weight MLP; writes s (bf16, padded to 12) at dst-sorted pos.
// (field-proven since round 2)
// ---------------------------------------------------------------------------
__global__ __launch_bounds__(256) void k_edge_mlp(
    const float* __restrict__ edge_attr, const float* __restrict__ edge_sh,
    const float* __restrict__ W1, const float* __restrict__ b1,
    const float* __restrict__ W2, const float* __restrict__ b2,
    const u32* __restrict__ rank,
    u16* __restrict__ s_sorted)            // [NE][12] bf16 at rank[e]
{
    __shared__ float sAttr[256 * 36];
    const int t  = threadIdx.x;
    const int e0 = blockIdx.x * 256;

    const float* ga = edge_attr + (size_t)e0 * 32;
    #pragma unroll
    for (int k = 0; k < 32; ++k) {
        int i = k * 256 + t;
        sAttr[(i >> 5) * 36 + (i & 31)] = ga[i];
    }
    __syncthreads();

    float a[32];
    #pragma unroll
    for (int q = 0; q < 8; ++q) {
        float4 v = *(const float4*)&sAttr[t * 36 + q * 4];
        a[4*q+0] = v.x; a[4*q+1] = v.y; a[4*q+2] = v.z; a[4*q+3] = v.w;
    }

    float hid[64];
    #pragma unroll
    for (int h = 0; h < 64; ++h) hid[h] = b1[h];
    for (int d = 0; d < 32; ++d) {
        const float ad = a[d];
        const float* wr = W1 + d * 64;
        #pragma unroll
        for (int h = 0; h < 64; ++h) hid[h] += ad * wr[h];
    }

    float w[9];
    #pragma unroll
    for (int m = 0; m < 9; ++m) w[m] = b2[m];
    for (int h = 0; h < 64; ++h) {
        const float hv = silu_f(hid[h]);
        const float* w2r = W2 + h * 9;
        #pragma unroll
        for (int m = 0; m < 9; ++m) w[m] += hv * w2r[m];
    }

    const size_t e = (size_t)e0 + t;
    const float* sh = edge_sh + e * 9;
    u16 sw[12];
    #pragma unroll
    for (int m = 0; m < 9; ++m) sw[m] = f2bf(sh[m] * w[m]);
    sw[9] = sw[10] = sw[11] = 0;

    u16* dp = s_sorted + (size_t)rank[e] * 12;
    ushort4 v0{sw[0], sw[1], sw[2],  sw[3]};
    ushort4 v1{sw[4], sw[5], sw[6],  sw[7]};
    ushort4 v2{sw[8], sw[9], sw[10], sw[11]};
    *(ushort4*)(dp + 0) = v0;
    *(ushort4*)(dp + 4) = v1;
    *(ushort4*)(dp + 8) = v2;
}

// ---------------------------------------------------------------------------
// K3: MFMA combine (r6-proven math path) + LDS segmented reduce.
// Block = 256 dst-sorted edges, 4 waves, each wave 4 A-tiles of 16 edges.
// A-frag built from feat[src]*s via proven f2bf packing; B from WtT.
// C tiles -> LDS msg[256][68] -> per-node partial sums -> ~17 atomics/block.
// ---------------------------------------------------------------------------
__global__ __launch_bounds__(256, 2) void k_combine_mfma(
    const u32* __restrict__ ssrc, const u16* __restrict__ sdst,
    const u32* __restrict__ row,  const u16* __restrict__ s_sorted,
    const float* __restrict__ feat, const u16* __restrict__ WtT,
    float* __restrict__ out)
{
    __shared__ float msg[256 * 68];
    const int t  = threadIdx.x;
    const int w  = t >> 6;
    const int l  = t & 63;
    const int p0 = blockIdx.x * 256;
    const int rbase = w << 6;

    // this lane's A-row edge for each et-tile
    u32 srcr[4];
    float sreg[4][9];
    #pragma unroll
    for (int et = 0; et < 4; ++et) {
        const int p = p0 + rbase + (et << 4) + (l & 15);
        srcr[et] = ssrc[p];
        const u16* sp = s_sorted + (size_t)p * 12;
        #pragma unroll
        for (int m = 0; m < 9; ++m) sreg[et][m] = bf2f(sp[m]);
    }

    f32x4 acc[4][4] = {};
    #pragma unroll
    for (int fhalf = 0; fhalf < 2; ++fhalf) {
        float hv[4][8];
        #pragma unroll
        for (int et = 0; et < 4; ++et) {
            const float* hp = feat + (size_t)srcr[et] * 64 + (fhalf << 5) + ((l >> 4) << 3);
            float4 v0 = *(const float4*)hp;
            float4 v1 = *(const float4*)(hp + 4);
            hv[et][0] = v0.x; hv[et][1] = v0.y; hv[et][2] = v0.z; hv[et][3] = v0.w;
            hv[et][4] = v1.x; hv[et][5] = v1.y; hv[et][6] = v1.z; hv[et][7] = v1.w;
        }
        #pragma unroll
        for (int m = 0; m < 9; ++m) {
            const int tt = (m << 1) + fhalf;          // K-slice: k = tt*32 ..
            short8 bfr[4];
            #pragma unroll
            for (int gt = 0; gt < 4; ++gt)
                bfr[gt] = *(const short8*)(WtT +
                    (size_t)(((gt << 4) + (l & 15)) * 576 + tt * 32 + ((l >> 4) << 3)));
            #pragma unroll
            for (int et = 0; et < 4; ++et) {
                const float s = sreg[et][m];
                union { u32 u[4]; short8 v; } A;
                A.u[0] = pk_bf16(hv[et][0] * s, hv[et][1] * s);
                A.u[1] = pk_bf16(hv[et][2] * s, hv[et][3] * s);
                A.u[2] = pk_bf16(hv[et][4] * s, hv[et][5] * s);
                A.u[3] = pk_bf16(hv[et][6] * s, hv[et][7] * s);
                #pragma unroll
                for (int gt = 0; gt < 4; ++gt)
                    acc[et][gt] = __builtin_amdgcn_mfma_f32_16x16x32_bf16(A.v, bfr[gt], acc[et][gt], 0, 0, 0);
            }
        }
    }

    // ---- C tiles -> LDS msg[256][68] (each thread writes disjoint cells) ----
    #pragma unroll
    for (int et = 0; et < 4; ++et)
        #pragma unroll
        for (int gt = 0; gt < 4; ++gt)
            #pragma unroll
            for (int rg = 0; rg < 4; ++rg) {
                int rloc = rbase + (et << 4) + ((l >> 4) << 2) + rg;   // C row = edge
                int col  = (gt << 4) + (l & 15);                       // C col = g
                msg[rloc * 68 + col] = acc[et][gt][rg];
            }
    __syncthreads();

    // ---- segmented per-node reduction; one atomic per (node,g) per block ----
    const int dfirst = sdst[p0];
    const int dlast  = sdst[p0 + 255];
    for (int n = dfirst + w; n <= dlast; n += 4) {
        int a = (int)row[n]     - p0; if (a < 0)   a = 0;
        int b = (int)row[n + 1] - p0; if (b > 256) b = 256;
        if (a < b) {
            float v = 0.f;
            for (int p = a; p < b; ++p) v += msg[p * 68 + l];
            atomicAdd(out + (size_t)n * 64 + l, v * 0.25f);    // 1/sqrt(16)
        }
    }
}

// ---------------------------------------------------------------------------
// K4: FiLM, in-place on d_out.
// ---------------------------------------------------------------------------
__global__ __launch_bounds__(256) void k_film(
    const float* __restrict__ c_noise,
    const float* __restrict__ Wn1, const float* __restrict__ bn1,
    const float* __restrict__ Wn2, const float* __restrict__ bn2,
    float* __restrict__ out)
{
    const int n    = (blockIdx.x * 256 + threadIdx.x) >> 6;
    const int lane = threadIdx.x & 63;
    const float c  = c_noise[n];
    const float hid = silu_f(fmaf(c, Wn1[lane], bn1[lane]));
    float g = bn2[lane], b = bn2[64 + lane];
    for (int h = 0; h < 64; ++h) {
        const float hv = __shfl(hid, h, 64);
        g = fmaf(hv, Wn2[h * 128 + lane],      g);
        b = fmaf(hv, Wn2[h * 128 + 64 + lane], b);
    }
    const size_t i = (size_t)n * 64 + lane;
    out[i] = fmaf(out[i], 1.f + g, b);
}

// ---------------------------------------------------------------------------
extern "C" void kernel_launch(void* const* d_in, const int* in_sizes, int n_in,
                              void* d_out, int out_size, void* d_ws, size_t ws_size,
                              hipStream_t stream) {
    const float* features   = (const float*)d_in[0];
    const int*   edge_index = (const int*)  d_in[1];
    const float* edge_attr  = (const float*)d_in[2];
    const float* edge_sh    = (const float*)d_in[3];
    const float* c_noise    = (const float*)d_in[4];
    const float* W1  = (const float*)d_in[5];
    const float* b1  = (const float*)d_in[6];
    const float* W2  = (const float*)d_in[7];
    const float* b2  = (const float*)d_in[8];
    const float* Wtp = (const float*)d_in[9];
    const float* Wn1 = (const float*)d_in[10];
    const float* bn1 = (const float*)d_in[11];
    const float* Wn2 = (const float*)d_in[12];
    const float* bn2 = (const float*)d_in[13];
    float* out = (float*)d_out;

    char* ws = (char*)d_ws;
    u16* s_sorted = (u16*)(ws);                    // 19,200,000 B
    u32* ssrc     = (u32*)(ws + 19200000);         //  3,200,000 B
    u32* rank     = (u32*)(ws + 22400000);         //  3,200,000 B
    u16* sdst     = (u16*)(ws + 25600000);         //  1,600,000 B
    u32* row      = (u32*)(ws + 27200000);         //    200,016 B (NN+1)
    u32* rowcur   = (u32*)(ws + 27400016);         //    200,000 B
    u32* cnt      = (u32*)(ws + 27600016);         //    200,000 B
    u32* part     = (u32*)(ws + 27800016);         //      1,024 B
    u16* WtT      = (u16*)(ws + 27801040);         //     73,728 B  (end ~27.9 MB)

    const int nparts = (NN + 255) / 256;           // 196

    hipMemsetAsync(cnt, 0, (size_t)NN * 4, stream);
    hipMemsetAsync(out, 0, (size_t)NN * 64 * sizeof(float), stream);

    k_hist   <<<NE / 256, 256, 0, stream>>>(edge_index, cnt);
    k_scan_a <<<nparts, 256, 0, stream>>>(cnt, part);
    k_scan_b <<<1, 256, 0, stream>>>(part, nparts);
    k_scan_c <<<nparts, 256, 0, stream>>>(cnt, part, row, rowcur);
    k_scatter<<<NE / 256, 256, 0, stream>>>(edge_index, rowcur, rank, ssrc, sdst);

    k_wt      <<<(576 * 64) / 256, 256, 0, stream>>>(Wtp, WtT);
    k_edge_mlp<<<NE / 256, 256, 0, stream>>>(edge_attr, edge_sh, W1, b1, W2, b2, rank, s_sorted);

    k_combine_mfma<<<NE / 256, 256, 0, stream>>>(ssrc, sdst, row, s_sorted,
                                                 features, WtT, out);

    k_film<<<(NN * 64) / 256, 256, 0, stream>>>(c_noise, Wn1, bn1, Wn2, bn2, out);
}